// Round 1
// baseline (249.466 us; speedup 1.0000x reference)
//
#include <hip/hip_runtime.h>
#include <hip/hip_bf16.h>

// LBONorm: fused LayerNorm + low-rank diffusion smoothing.
// rows = B*S = 16384, d = 2048 (fp32), rank = 8.
// One block = 8 rows; thread t owns columns {4t..4t+3, 1024+4t..4t+3}.
// V is register-resident per thread (8 cols x 8 ranks = 64 VGPRs),
// amortized over the 8 rows -> h read once, out written once (HBM-bound).

constexpr int D       = 2048;
constexpr int RANK    = 8;
constexpr int BLOCK   = 256;
constexpr int ROWS_PB = 8;
constexpr float LN_EPS = 1e-5f;

__device__ __forceinline__ float wred(float v) {
    #pragma unroll
    for (int off = 32; off > 0; off >>= 1) v += __shfl_xor(v, off, 64);
    return v;
}

__global__ __launch_bounds__(BLOCK, 4)
void lbonorm_kernel(const float* __restrict__ h,
                    const float* __restrict__ gamma,
                    const float* __restrict__ beta,
                    const float* __restrict__ V,
                    const float* __restrict__ eta_p,
                    float* __restrict__ out,
                    float* __restrict__ e_out)
{
    const int t    = threadIdx.x;
    const int lane = t & 63;
    const int wave = t >> 6;

    const int c0 = t * 4;           // first 4 owned columns
    const int c1 = D / 2 + t * 4;   // second 4 owned columns

    __shared__ float red[4][10];
    __shared__ float bcast[10];
    __shared__ float vsum_s[RANK];

    // ---- preload V columns into registers: vreg[g][j][r] = V[r][cg+j]
    float vreg[2][4][RANK];
    #pragma unroll
    for (int r = 0; r < RANK; ++r) {
        float4 a = *reinterpret_cast<const float4*>(V + (size_t)r * D + c0);
        float4 b = *reinterpret_cast<const float4*>(V + (size_t)r * D + c1);
        vreg[0][0][r] = a.x; vreg[0][1][r] = a.y; vreg[0][2][r] = a.z; vreg[0][3][r] = a.w;
        vreg[1][0][r] = b.x; vreg[1][1][r] = b.y; vreg[1][2][r] = b.z; vreg[1][3][r] = b.w;
    }

    // ---- per-rank column sums of V (needed for c[r] = inv*(dot[r] - mu*Vsum[r]))
    {
        float vs[RANK];
        #pragma unroll
        for (int r = 0; r < RANK; ++r) {
            vs[r] = vreg[0][0][r] + vreg[0][1][r] + vreg[0][2][r] + vreg[0][3][r]
                  + vreg[1][0][r] + vreg[1][1][r] + vreg[1][2][r] + vreg[1][3][r];
            vs[r] = wred(vs[r]);
        }
        if (lane == 0) {
            #pragma unroll
            for (int r = 0; r < RANK; ++r) red[wave][r] = vs[r];
        }
        __syncthreads();
        if (t < RANK) vsum_s[t] = red[0][t] + red[1][t] + red[2][t] + red[3][t];
        __syncthreads();
    }

    const float eta = fminf(fmaxf(eta_p[0], 0.0f), 0.5f);

    // gamma/beta for the owned columns (loop-invariant across rows)
    const float4 g0 = *reinterpret_cast<const float4*>(gamma + c0);
    const float4 g1 = *reinterpret_cast<const float4*>(gamma + c1);
    const float4 b0 = *reinterpret_cast<const float4*>(beta + c0);
    const float4 b1 = *reinterpret_cast<const float4*>(beta + c1);
    const float gam[2][4] = {{g0.x,g0.y,g0.z,g0.w},{g1.x,g1.y,g1.z,g1.w}};
    const float bet[2][4] = {{b0.x,b0.y,b0.z,b0.w},{b1.x,b1.y,b1.z,b1.w}};

    const size_t row0 = (size_t)blockIdx.x * ROWS_PB;

    for (int rr = 0; rr < ROWS_PB; ++rr) {
        const size_t row = row0 + rr;
        const float* hrow = h + row * (size_t)D;

        float4 ha = *reinterpret_cast<const float4*>(hrow + c0);
        float4 hb = *reinterpret_cast<const float4*>(hrow + c1);
        float hr[2][4] = {{ha.x,ha.y,ha.z,ha.w},{hb.x,hb.y,hb.z,hb.w}};

        // ---- single pass: s, s2, dot[r] = sum h*V[r]
        float vals[10];
        {
            float s = 0.f, s2 = 0.f;
            #pragma unroll
            for (int g = 0; g < 2; ++g)
                #pragma unroll
                for (int j = 0; j < 4; ++j) {
                    s += hr[g][j];
                    s2 = fmaf(hr[g][j], hr[g][j], s2);
                }
            vals[0] = s; vals[1] = s2;
            #pragma unroll
            for (int r = 0; r < RANK; ++r) {
                float dp = 0.f;
                #pragma unroll
                for (int g = 0; g < 2; ++g)
                    #pragma unroll
                    for (int j = 0; j < 4; ++j)
                        dp = fmaf(hr[g][j], vreg[g][j][r], dp);
                vals[2 + r] = dp;
            }
        }
        #pragma unroll
        for (int n = 0; n < 10; ++n) vals[n] = wred(vals[n]);

        __syncthreads();                 // guard red[] reuse from previous row
        if (lane == 0) {
            #pragma unroll
            for (int n = 0; n < 10; ++n) red[wave][n] = vals[n];
        }
        __syncthreads();
        if (t < 10) bcast[t] = red[0][t] + red[1][t] + red[2][t] + red[3][t];
        __syncthreads();

        const float mu  = bcast[0] * (1.0f / D);
        const float var = fmaxf(bcast[1] * (1.0f / D) - mu * mu, 0.0f);
        const float inv = rsqrtf(var + LN_EPS);
        float c[RANK];
        #pragma unroll
        for (int r = 0; r < RANK; ++r)
            c[r] = inv * (bcast[2 + r] - mu * vsum_s[r]);

        // ---- epilogue: proj, delta, e_curv, smooth, affine, store
        float e = 0.f;
        float ov[2][4];
        #pragma unroll
        for (int g = 0; g < 2; ++g) {
            #pragma unroll
            for (int j = 0; j < 4; ++j) {
                const float hh = (hr[g][j] - mu) * inv;
                float proj = 0.f;
                #pragma unroll
                for (int r = 0; r < RANK; ++r)
                    proj = fmaf(c[r], vreg[g][j][r], proj);
                const float delta = hh - proj;
                e = fmaf(delta, delta, e);
                const float sm = fmaf(-eta, delta, hh);
                ov[g][j] = fmaf(sm, gam[g][j], bet[g][j]);
            }
        }
        float* orow = out + row * (size_t)D;
        *reinterpret_cast<float4*>(orow + c0) = make_float4(ov[0][0], ov[0][1], ov[0][2], ov[0][3]);
        *reinterpret_cast<float4*>(orow + c1) = make_float4(ov[1][0], ov[1][1], ov[1][2], ov[1][3]);

        e = wred(e);
        if (lane == 0) red[wave][0] = e;
        __syncthreads();
        if (t == 0) e_out[row] = red[0][0] + red[1][0] + red[2][0] + red[3][0];
        // next iteration's first __syncthreads guards red[] for reuse
    }
}

extern "C" void kernel_launch(void* const* d_in, const int* in_sizes, int n_in,
                              void* d_out, int out_size, void* d_ws, size_t ws_size,
                              hipStream_t stream) {
    const float* h     = (const float*)d_in[0];
    const float* gamma = (const float*)d_in[1];
    const float* beta  = (const float*)d_in[2];
    const float* V     = (const float*)d_in[3];
    const float* eta   = (const float*)d_in[4];
    float* out = (float*)d_out;

    const int d = in_sizes[1];                       // 2048
    const long long rows = in_sizes[0] / d;          // 16384
    float* e_out = out + (size_t)rows * d;

    dim3 grid((unsigned)(rows / ROWS_PB));
    lbonorm_kernel<<<grid, BLOCK, 0, stream>>>(h, gamma, beta, V, eta, out, e_out);
}

// Round 2
// 81.550 us; speedup vs baseline: 3.0591x; 3.0591x over previous
//
#include <hip/hip_runtime.h>
#include <hip/hip_bf16.h>

// LBONorm: fused LayerNorm + low-rank diffusion smoothing.
// rows = B*S = 16384, d = 2048 (fp32), rank = 8.
// One block = 8 rows; thread t owns columns {4t..4t+3, 1024+4t..4t+3}.
// V register-resident (64 VGPR/thread), amortized over 8 rows.
// Round 1 lesson: __launch_bounds__(256,4) capped VGPR at 128 -> spill
// (FETCH 606MB vs 135MB ideal). Need ~140 VGPR -> cap at (256,2).

constexpr int D       = 2048;
constexpr int RANK    = 8;
constexpr int BLOCK   = 256;
constexpr int ROWS_PB = 8;
constexpr float LN_EPS = 1e-5f;

__device__ __forceinline__ float wred(float v) {
    #pragma unroll
    for (int off = 32; off > 0; off >>= 1) v += __shfl_xor(v, off, 64);
    return v;
}

__global__ __launch_bounds__(BLOCK, 2)
void lbonorm_kernel(const float* __restrict__ h,
                    const float* __restrict__ gamma,
                    const float* __restrict__ beta,
                    const float* __restrict__ V,
                    const float* __restrict__ eta_p,
                    float* __restrict__ out,
                    float* __restrict__ e_out)
{
    const int t    = threadIdx.x;
    const int lane = t & 63;
    const int wave = t >> 6;

    const int c0 = t * 4;           // first 4 owned columns
    const int c1 = D / 2 + t * 4;   // second 4 owned columns

    // red[w][0..9]  = per-wave partials (s, s2, dot[0..7]) for current row
    // red[w][10]    = per-wave partial of e_curv (chained to next row's barrier)
    __shared__ float red[4][12];
    __shared__ float vsum_s[RANK];

    // ---- preload V columns into registers: vreg[g][j][r] = V[r][cg+j]
    float vreg[2][4][RANK];
    #pragma unroll
    for (int r = 0; r < RANK; ++r) {
        float4 a = *reinterpret_cast<const float4*>(V + (size_t)r * D + c0);
        float4 b = *reinterpret_cast<const float4*>(V + (size_t)r * D + c1);
        vreg[0][0][r] = a.x; vreg[0][1][r] = a.y; vreg[0][2][r] = a.z; vreg[0][3][r] = a.w;
        vreg[1][0][r] = b.x; vreg[1][1][r] = b.y; vreg[1][2][r] = b.z; vreg[1][3][r] = b.w;
    }

    // ---- per-rank column sums of V (for c[r] = inv*(dot[r] - mu*Vsum[r]))
    {
        float vs[RANK];
        #pragma unroll
        for (int r = 0; r < RANK; ++r) {
            vs[r] = vreg[0][0][r] + vreg[0][1][r] + vreg[0][2][r] + vreg[0][3][r]
                  + vreg[1][0][r] + vreg[1][1][r] + vreg[1][2][r] + vreg[1][3][r];
            vs[r] = wred(vs[r]);
        }
        if (lane == 0) {
            #pragma unroll
            for (int r = 0; r < RANK; ++r) red[wave][r] = vs[r];
        }
        __syncthreads();
        if (t < RANK) vsum_s[t] = red[0][t] + red[1][t] + red[2][t] + red[3][t];
        __syncthreads();
    }

    const float eta = fminf(fmaxf(eta_p[0], 0.0f), 0.5f);

    const float4 g0 = *reinterpret_cast<const float4*>(gamma + c0);
    const float4 g1 = *reinterpret_cast<const float4*>(gamma + c1);
    const float4 b0 = *reinterpret_cast<const float4*>(beta + c0);
    const float4 b1 = *reinterpret_cast<const float4*>(beta + c1);
    const float gam[2][4] = {{g0.x,g0.y,g0.z,g0.w},{g1.x,g1.y,g1.z,g1.w}};
    const float bet[2][4] = {{b0.x,b0.y,b0.z,b0.w},{b1.x,b1.y,b1.z,b1.w}};

    const size_t row0 = (size_t)blockIdx.x * ROWS_PB;

    // software prefetch: current row lives in (ha,hb), next row issued early
    float4 ha = *reinterpret_cast<const float4*>(h + row0 * (size_t)D + c0);
    float4 hb = *reinterpret_cast<const float4*>(h + row0 * (size_t)D + c1);

    for (int rr = 0; rr < ROWS_PB; ++rr) {
        const size_t row = row0 + rr;
        const size_t nrow = row0 + (rr + 1 < ROWS_PB ? rr + 1 : rr);
        float4 na = *reinterpret_cast<const float4*>(h + nrow * (size_t)D + c0);
        float4 nb = *reinterpret_cast<const float4*>(h + nrow * (size_t)D + c1);

        const float hr[2][4] = {{ha.x,ha.y,ha.z,ha.w},{hb.x,hb.y,hb.z,hb.w}};

        // ---- single pass over registers: s, s2, dot[r]
        float vals[10];
        {
            float s = 0.f, s2 = 0.f;
            #pragma unroll
            for (int g = 0; g < 2; ++g)
                #pragma unroll
                for (int j = 0; j < 4; ++j) {
                    s += hr[g][j];
                    s2 = fmaf(hr[g][j], hr[g][j], s2);
                }
            vals[0] = s; vals[1] = s2;
            #pragma unroll
            for (int r = 0; r < RANK; ++r) {
                float dp = 0.f;
                #pragma unroll
                for (int g = 0; g < 2; ++g)
                    #pragma unroll
                    for (int j = 0; j < 4; ++j)
                        dp = fmaf(hr[g][j], vreg[g][j][r], dp);
                vals[2 + r] = dp;
            }
        }
        #pragma unroll
        for (int n = 0; n < 10; ++n) vals[n] = wred(vals[n]);

        __syncthreads();                       // A: prev-row red[] reads done
        if (lane == 0) {
            #pragma unroll
            for (int n = 0; n < 10; ++n) red[wave][n] = vals[n];
        }
        if (t == 0 && rr > 0)                  // prev row's e_curv (slot 10 safe until after B)
            e_out[row - 1] = red[0][10] + red[1][10] + red[2][10] + red[3][10];
        __syncthreads();                       // B: red[0..9] visible to all

        float tot[10];
        #pragma unroll
        for (int n = 0; n < 10; ++n)
            tot[n] = red[0][n] + red[1][n] + red[2][n] + red[3][n];

        const float mu  = tot[0] * (1.0f / D);
        const float var = fmaxf(tot[1] * (1.0f / D) - mu * mu, 0.0f);
        const float inv = rsqrtf(var + LN_EPS);
        float c[RANK];
        #pragma unroll
        for (int r = 0; r < RANK; ++r)
            c[r] = inv * (tot[2 + r] - mu * vsum_s[r]);

        // ---- epilogue: proj, delta, e_curv, smooth, affine, store
        float e = 0.f;
        float ov[2][4];
        #pragma unroll
        for (int g = 0; g < 2; ++g) {
            #pragma unroll
            for (int j = 0; j < 4; ++j) {
                const float hh = (hr[g][j] - mu) * inv;
                float proj = 0.f;
                #pragma unroll
                for (int r = 0; r < RANK; ++r)
                    proj = fmaf(c[r], vreg[g][j][r], proj);
                const float delta = hh - proj;
                e = fmaf(delta, delta, e);
                const float sm = fmaf(-eta, delta, hh);
                ov[g][j] = fmaf(sm, gam[g][j], bet[g][j]);
            }
        }
        float* orow = out + row * (size_t)D;
        *reinterpret_cast<float4*>(orow + c0) = make_float4(ov[0][0], ov[0][1], ov[0][2], ov[0][3]);
        *reinterpret_cast<float4*>(orow + c1) = make_float4(ov[1][0], ov[1][1], ov[1][2], ov[1][3]);

        e = wred(e);
        if (lane == 0) red[wave][10] = e;      // read at next row's A/B window

        ha = na; hb = nb;
    }

    __syncthreads();
    if (t == 0)
        e_out[row0 + ROWS_PB - 1] = red[0][10] + red[1][10] + red[2][10] + red[3][10];
}

extern "C" void kernel_launch(void* const* d_in, const int* in_sizes, int n_in,
                              void* d_out, int out_size, void* d_ws, size_t ws_size,
                              hipStream_t stream) {
    const float* h     = (const float*)d_in[0];
    const float* gamma = (const float*)d_in[1];
    const float* beta  = (const float*)d_in[2];
    const float* V     = (const float*)d_in[3];
    const float* eta   = (const float*)d_in[4];
    float* out = (float*)d_out;

    const int d = in_sizes[1];                       // 2048
    const long long rows = in_sizes[0] / d;          // 16384
    float* e_out = out + (size_t)rows * d;

    dim3 grid((unsigned)(rows / ROWS_PB));
    lbonorm_kernel<<<grid, BLOCK, 0, stream>>>(h, gamma, beta, V, eta, out, e_out);
}